// Round 14
// baseline (580.756 us; speedup 1.0000x reference)
//
#include <hip/hip_runtime.h>
#include <math.h>

#define N_    16
#define CIN_  16
#define T_    512
#define V_    200
#define K_    3
#define COUT_ 64
#define H_    64
#define G_    256  // 4*H

// Workspace layout (float offsets):
//   a  : [0, 600)                 a[k][v] = sum_w A[k,v,w] / V
//   sa : [640, 643)               sa[k] = sum_{v,w} A[k,v,w] / V
//   xa : [1024, 1024+16*512*48)   xa[n][t][k*16+ci]
//   xW : [WS_XW, +512*16*256)     xW[t][n][g]  (gate pre-activations, input side)
#define WS_A  0
#define WS_SA 640
#define WS_XA 1024
#define WS_XW (WS_XA + N_ * T_ * K_ * CIN_)

typedef __attribute__((ext_vector_type(4))) float f32x4;

// fast activations: v_exp_f32-based, ~1e-6 rel err, saturate correctly
__device__ __forceinline__ float fast_sig(float x) {
    return __builtin_amdgcn_rcpf(1.f + __expf(-x));
}
__device__ __forceinline__ float fast_tanh(float x) {
    return fmaf(-2.f, __builtin_amdgcn_rcpf(1.f + __expf(2.f * x)), 1.f);
}

// ---------------------------------------------------------------------------
// Kernel 1 (fused prep): blocks [0, NCOPY) copy A->out[16:] (blocks 0-2 also
// compute a[k][v]); blocks NCOPY+k (k=0..2) reduce A[k] to sa[k].
#define NCOPY ((K_ * V_ * V_ + 255) / 256)
__global__ __launch_bounds__(256) void prep_kernel(const float* __restrict__ A,
                                                   float* __restrict__ out,
                                                   float* __restrict__ ws) {
    int b = blockIdx.x;
    if (b < NCOPY) {
        int tid = b * 256 + threadIdx.x;
        if (tid < K_ * V_ * V_) out[16 + tid] = A[tid];
        if (tid < K_ * V_) {
            const float* row = A + (long)tid * V_;
            float s = 0.f;
            for (int w = 0; w < V_; ++w) s += row[w];
            ws[WS_A + tid] = s * (1.0f / V_);
        }
    } else {
        int k = b - NCOPY;                      // 0..2
        const float* Ak = A + (long)k * V_ * V_;
        float s = 0.f;
        for (int i = threadIdx.x; i < V_ * V_; i += 256) s += Ak[i];
        #pragma unroll
        for (int m = 1; m < 64; m <<= 1) s += __shfl_xor(s, m);
        __shared__ float red[4];
        if ((threadIdx.x & 63) == 0) red[threadIdx.x >> 6] = s;
        __syncthreads();
        if (threadIdx.x == 0)
            ws[WS_SA + k] = (red[0] + red[1] + red[2] + red[3]) * (1.0f / V_);
    }
}

// ---------------------------------------------------------------------------
// Kernel 2 (tiled xa): xa[n][t][k*16+ci] = sum_v x[n][ci][t][v] * a[k][v]
#define TT 64
#define PADV 204
__global__ __launch_bounds__(256) void xa_kernel(const float* __restrict__ x,
                                                 float* __restrict__ ws) {
    __shared__ __align__(16) float xt[TT * PADV];
    __shared__ __align__(16) float aS[K_ * V_];
    int tid = threadIdx.x;
    int b = blockIdx.x;
    int tchunk = b & 7;
    int ci = (b >> 3) & 15;
    int n = b >> 7;
    int t0 = tchunk * TT;

    for (int i = tid; i < K_ * V_; i += 256) aS[i] = ws[WS_A + i];

    const float4* xg4 =
        (const float4*)(x + ((long)(n * CIN_ + ci) * T_ + t0) * V_);
    for (int j = tid; j < TT * (V_ / 4); j += 256) {
        float4 v = xg4[j];
        int t = j / (V_ / 4), v4 = (j % (V_ / 4)) * 4;
        *(float4*)(xt + t * PADV + v4) = v;
    }
    __syncthreads();

    int t_local = tid & 63;
    int k = tid >> 6;            // waves 0..2 active, wave 3 idle
    if (k < K_) {
        const float* xr = xt + t_local * PADV;
        const float* ar = aS + k * V_;
        float a0 = 0.f, a1 = 0.f, a2 = 0.f, a3 = 0.f;
        #pragma unroll 5
        for (int v4 = 0; v4 < V_; v4 += 4) {
            float4 xv = *(const float4*)(xr + v4);
            float4 av = *(const float4*)(ar + v4);   // wave-uniform broadcast
            a0 = fmaf(xv.x, av.x, a0);
            a1 = fmaf(xv.y, av.y, a1);
            a2 = fmaf(xv.z, av.z, a2);
            a3 = fmaf(xv.w, av.w, a3);
        }
        float s = (a0 + a1) + (a2 + a3);
        ws[WS_XA + ((long)n * T_ + (t0 + t_local)) * (K_ * CIN_) + k * CIN_ + ci] = s;
    }
}

// ---------------------------------------------------------------------------
// Kernel 3 (fused seq + input-gate GEMM): ONE block per t (512 blocks).
__global__ __launch_bounds__(256) void seqgates_kernel(
    const float* __restrict__ W_gcn, const float* __restrict__ b_gcn,
    const float* __restrict__ W_ih, const float* __restrict__ b_ih,
    const float* __restrict__ b_hh, float* __restrict__ ws) {
    int t = blockIdx.x;
    int tid = threadIdx.x;
    __shared__ float xaS[N_][K_ * CIN_];
    __shared__ __align__(16) float seqS[N_][COUT_];
    __shared__ float saS[K_];

    if (tid < K_) saS[tid] = ws[WS_SA + tid];
    #pragma unroll
    for (int r = 0; r < 3; ++r) {
        int i = tid + r * 256;
        if (i < N_ * K_ * CIN_) {
            int n = i / (K_ * CIN_), kc = i % (K_ * CIN_);
            xaS[n][kc] = ws[WS_XA + (long)(n * T_ + t) * (K_ * CIN_) + kc];
        }
    }
    __syncthreads();

    // Phase 1: thread (n = tid>>4, c0 = (tid&15)*4) computes 4 seq entries.
    {
        int n = tid >> 4, c0 = (tid & 15) * 4;
        #pragma unroll
        for (int cc = 0; cc < 4; ++cc) {
            int c = c0 + cc;
            float s = 0.f;
            #pragma unroll
            for (int k = 0; k < K_; ++k) {
                s = fmaf(b_gcn[k * COUT_ + c], saS[k], s);
                const float* wrow = W_gcn + (long)(k * COUT_ + c) * CIN_;
                #pragma unroll
                for (int ci = 0; ci < CIN_; ++ci)
                    s = fmaf(wrow[ci], xaS[n][k * CIN_ + ci], s);
            }
            seqS[n][c] = s;
        }
    }
    __syncthreads();

    // Phase 2: thread g: 16 accumulators over n; W_ih row streamed as float4.
    {
        int g = tid;
        float acc[N_];
        #pragma unroll
        for (int n = 0; n < N_; ++n) acc[n] = 0.f;
        const float4* wrow4 = (const float4*)(W_ih + (long)g * H_);
        #pragma unroll
        for (int c4 = 0; c4 < H_ / 4; ++c4) {
            float4 w4 = wrow4[c4];
            #pragma unroll
            for (int n = 0; n < N_; ++n) {
                float4 s4 = ((const float4*)seqS[n])[c4];  // LDS broadcast
                acc[n] = fmaf(w4.x, s4.x, acc[n]);
                acc[n] = fmaf(w4.y, s4.y, acc[n]);
                acc[n] = fmaf(w4.z, s4.z, acc[n]);
                acc[n] = fmaf(w4.w, s4.w, acc[n]);
            }
        }
        float bias = b_ih[g] + b_hh[g];
        #pragma unroll
        for (int n = 0; n < N_; ++n)
            ws[WS_XW + (long)(t * N_ + n) * G_ + g] = acc[n] + bias;
    }
}

// ---------------------------------------------------------------------------
// Kernel 4: sequential LSTM scan — R12 structure, TWO batches per block.
// Evidence R3-R13: step time (~260-277us) is insensitive to weight tier,
// barrier count, and exchange mechanism -> latency-chain-bound (likely at
// reduced clock: measured 1284 nominal-cy/step vs ~600-cy chain model fits
// a ~1.1GHz actual clock). Latency-bound => idle issue slots => process 2
// batches per block: the 2nd batch's 64 FMAs share the SAME weight regs,
// its gbuf exchange runs in the same barrier window, and its activations
// run on wave 1 PARALLEL to batch A's on wave 0. Blocks 16 -> 8.
__global__ __launch_bounds__(256, 1) void lstm_kernel(
    const float* __restrict__ W_hh, const float* __restrict__ W_fc,
    const float* __restrict__ b_fc, const float* __restrict__ ws,
    float* __restrict__ out) {
    int nA = blockIdx.x * 2;      // batch A
    int nB = nA + 1;              // batch B
    int w = threadIdx.x >> 6;     // gate type (torch order: i,f,g,o)
    int lane = threadIdx.x & 63;  // gate index / h index

    // One-time, non-rematerializable load of this thread's W_hh row
    // (shared by both batches).
    const f32x4* wr = (const f32x4*)(W_hh + (long)(w * H_ + lane) * H_);
    f32x4 w0, w1, w2, w3, w4, w5, w6, w7, w8, w9, w10, w11, w12, w13, w14, w15;
    #define WLOAD(i) \
        asm volatile("global_load_dwordx4 %0, %1, off" : "=v"(w##i) : "v"(wr + i));
    WLOAD(0)  WLOAD(1)  WLOAD(2)  WLOAD(3)
    WLOAD(4)  WLOAD(5)  WLOAD(6)  WLOAD(7)
    WLOAD(8)  WLOAD(9)  WLOAD(10) WLOAD(11)
    WLOAD(12) WLOAD(13) WLOAD(14) WLOAD(15)
    #undef WLOAD
    asm volatile("s_waitcnt vmcnt(0)" ::: "memory");

    __shared__ __align__(16) float hSA[H_], hSB[H_];
    __shared__ float gbufA[4][H_], gbufB[4][H_];

    if (threadIdx.x < H_) { hSA[threadIdx.x] = 0.f; hSB[threadIdx.x] = 0.f; }
    float ccell = 0.f, hlast = 0.f;   // wave 0: batch A state; wave 1: batch B
    __syncthreads();

    const float* xwA = ws + WS_XW + (long)nA * G_ + (w * H_ + lane);
    const float* xwB = ws + WS_XW + (long)nB * G_ + (w * H_ + lane);
    float xA0 = xwA[0], xA1 = xwA[(long)N_ * G_];
    float xB0 = xwB[0], xB1 = xwB[(long)N_ * G_];

    for (int t = 0; t < T_; ++t) {
        float gateA = xA0, gateB = xB0;
        xA0 = xA1; xB0 = xB1;
        if (t + 2 < T_) {
            xA1 = xwA[(long)(t + 2) * N_ * G_];
            xB1 = xwB[(long)(t + 2) * N_ * G_];
        }

        // dots for both batches; weights shared, h via uniform b128 broadcast
        float a0 = 0.f, a1 = 0.f, a2 = 0.f, a3 = 0.f;
        float b0 = 0.f, b1 = 0.f, b2 = 0.f, b3 = 0.f;
        const float4* h4A = (const float4*)hSA;
        const float4* h4B = (const float4*)hSB;
        #define DOT4(i)                             \
            {                                       \
                float4 hvA = h4A[i];                \
                float4 hvB = h4B[i];                \
                a0 = fmaf(w##i[0], hvA.x, a0);      \
                a1 = fmaf(w##i[1], hvA.y, a1);      \
                a2 = fmaf(w##i[2], hvA.z, a2);      \
                a3 = fmaf(w##i[3], hvA.w, a3);      \
                b0 = fmaf(w##i[0], hvB.x, b0);      \
                b1 = fmaf(w##i[1], hvB.y, b1);      \
                b2 = fmaf(w##i[2], hvB.z, b2);      \
                b3 = fmaf(w##i[3], hvB.w, b3);      \
            }
        DOT4(0)  DOT4(1)  DOT4(2)  DOT4(3)
        DOT4(4)  DOT4(5)  DOT4(6)  DOT4(7)
        DOT4(8)  DOT4(9)  DOT4(10) DOT4(11)
        DOT4(12) DOT4(13) DOT4(14) DOT4(15)
        #undef DOT4
        gateA += (a0 + a1) + (a2 + a3);
        gateB += (b0 + b1) + (b2 + b3);

        gbufA[w][lane] = gateA;
        gbufB[w][lane] = gateB;
        __syncthreads();               // B1: gates visible
        if (w == 0) {                  // batch A activations on wave 0
            float iv = fast_sig(gbufA[0][lane]);
            float fv = fast_sig(gbufA[1][lane]);
            float gv = fast_tanh(gbufA[2][lane]);
            float ov = fast_sig(gbufA[3][lane]);
            ccell = fmaf(fv, ccell, iv * gv);
            hlast = ov * fast_tanh(ccell);
            hSA[lane] = hlast;
        } else if (w == 1) {           // batch B activations on wave 1
            float iv = fast_sig(gbufB[0][lane]);
            float fv = fast_sig(gbufB[1][lane]);
            float gv = fast_tanh(gbufB[2][lane]);
            float ov = fast_sig(gbufB[3][lane]);
            ccell = fmaf(fv, ccell, iv * gv);
            hlast = ov * fast_tanh(ccell);
            hSB[lane] = hlast;
        }
        __syncthreads();               // B2: new h visible
    }

    // finals: wave 0 -> out[nA], wave 1 -> out[nB]
    if (w < 2) {
        float p = hlast * W_fc[lane];
        #pragma unroll
        for (int m = 1; m < 64; m <<= 1) p += __shfl_xor(p, m);
        if (lane == 0) out[w == 0 ? nA : nB] = p + b_fc[0];
    }
}

// ---------------------------------------------------------------------------
extern "C" void kernel_launch(void* const* d_in, const int* in_sizes, int n_in,
                              void* d_out, int out_size, void* d_ws, size_t ws_size,
                              hipStream_t stream) {
    const float* x     = (const float*)d_in[0];
    const float* A     = (const float*)d_in[1];
    const float* W_gcn = (const float*)d_in[2];
    const float* b_gcn = (const float*)d_in[3];
    const float* W_ih  = (const float*)d_in[4];
    const float* W_hh  = (const float*)d_in[5];
    const float* b_ih  = (const float*)d_in[6];
    const float* b_hh  = (const float*)d_in[7];
    const float* W_fc  = (const float*)d_in[8];
    const float* b_fc  = (const float*)d_in[9];
    float* out = (float*)d_out;
    float* ws  = (float*)d_ws;

    // 1) fused: copy A->out, a[k][v], sa[k]
    prep_kernel<<<NCOPY + K_, 256, 0, stream>>>(A, out, ws);
    // 2) tiled xa (one block per (n, ci, 64-t chunk))
    xa_kernel<<<N_ * CIN_ * (T_ / TT), 256, 0, stream>>>(x, ws);
    // 3) fused seq + input-side gate GEMM (one block per t)
    seqgates_kernel<<<T_, 256, 0, stream>>>(W_gcn, b_gcn, W_ih, b_ih, b_hh, ws);
    // 4) sequential LSTM scan, 2 batches/block (8 blocks) + final FC
    lstm_kernel<<<N_ / 2, 256, 0, stream>>>(W_hh, W_fc, b_fc, ws, out);
}

// Round 15
// 468.864 us; speedup vs baseline: 1.2386x; 1.2386x over previous
//
#include <hip/hip_runtime.h>
#include <math.h>

#define N_    16
#define CIN_  16
#define T_    512
#define V_    200
#define K_    3
#define COUT_ 64
#define H_    64
#define G_    256  // 4*H

// Workspace layout (float offsets):
//   sa : [640, 643)               sa[k] = sum_{v,w} A[k,v,w] / V
//   xa : [1024, 1024+16*512*48)   xa[n][t][k*16+ci]
//   xW : [WS_XW, +512*16*256)     xW[t][n][g]  (gate pre-activations, input side)
#define WS_SA 640
#define WS_XA 1024
#define WS_XW (WS_XA + N_ * T_ * K_ * CIN_)

typedef __attribute__((ext_vector_type(4))) float f32x4;

// fast activations: v_exp_f32-based, ~1e-6 rel err, saturate correctly
__device__ __forceinline__ float fast_sig(float x) {
    return __builtin_amdgcn_rcpf(1.f + __expf(-x));
}
__device__ __forceinline__ float fast_tanh(float x) {
    return fmaf(-2.f, __builtin_amdgcn_rcpf(1.f + __expf(2.f * x)), 1.f);
}

// ---------------------------------------------------------------------------
// Kernel 1 (xa2, replaces prep+xa): blocks 0..255 = (n, ci): compute a[k][v]
// in-block (A is L2-resident, 480KB/block), then loop 8 x 64-t tiles of x
// through LDS and dot against a. Block 256 computes sa[k].
#define TT 64
#define PADV 204
__global__ __launch_bounds__(256) void xa2_kernel(const float* __restrict__ x,
                                                  const float* __restrict__ A,
                                                  float* __restrict__ ws) {
    int b = blockIdx.x;
    int tid = threadIdx.x;

    if (b == 256) {
        // sa[k] = sum(A[k]) / V — waves 0..2, lane-strided coalesced reads
        int k = tid >> 6, lane = tid & 63;
        if (k < K_) {
            const float* Ak = A + (long)k * V_ * V_;
            float s = 0.f;
            for (int i = lane; i < V_ * V_; i += 64) s += Ak[i];
            #pragma unroll
            for (int m = 1; m < 64; m <<= 1) s += __shfl_xor(s, m);
            if (lane == 0) ws[WS_SA + k] = s * (1.0f / V_);
        }
        return;
    }

    __shared__ __align__(16) float xt[TT * PADV];
    __shared__ __align__(16) float aS[K_ * V_];
    int n = b >> 4, ci = b & 15;

    // in-block a[k][v] = rowsum(A[k,v,:]) / V  (rows are 200 contiguous floats)
    for (int r = tid; r < K_ * V_; r += 256) {
        const float4* row = (const float4*)(A + (long)r * V_);
        float s0 = 0.f, s1 = 0.f, s2 = 0.f, s3 = 0.f;
        #pragma unroll 10
        for (int j = 0; j < V_ / 4; ++j) {
            float4 v = row[j];
            s0 += v.x; s1 += v.y; s2 += v.z; s3 += v.w;
        }
        aS[r] = ((s0 + s1) + (s2 + s3)) * (1.0f / V_);
    }
    __syncthreads();

    int t_local = tid & 63;
    int k = tid >> 6;            // waves 0..2 active in the dot, wave 3 idle

    for (int tc = 0; tc < T_ / TT; ++tc) {
        int t0 = tc * TT;
        // coalesced float4 load of the 64x200 tile
        const float4* xg4 =
            (const float4*)(x + ((long)(n * CIN_ + ci) * T_ + t0) * V_);
        for (int j = tid; j < TT * (V_ / 4); j += 256) {
            float4 v = xg4[j];
            int t = j / (V_ / 4), v4 = (j % (V_ / 4)) * 4;
            *(float4*)(xt + t * PADV + v4) = v;
        }
        __syncthreads();

        if (k < K_) {
            const float* xr = xt + t_local * PADV;
            const float* ar = aS + k * V_;
            float a0 = 0.f, a1 = 0.f, a2 = 0.f, a3 = 0.f;
            #pragma unroll 5
            for (int v4 = 0; v4 < V_; v4 += 4) {
                float4 xv = *(const float4*)(xr + v4);
                float4 av = *(const float4*)(ar + v4);   // wave-uniform bcast
                a0 = fmaf(xv.x, av.x, a0);
                a1 = fmaf(xv.y, av.y, a1);
                a2 = fmaf(xv.z, av.z, a2);
                a3 = fmaf(xv.w, av.w, a3);
            }
            float s = (a0 + a1) + (a2 + a3);
            ws[WS_XA + ((long)n * T_ + (t0 + t_local)) * (K_ * CIN_) +
               k * CIN_ + ci] = s;
        }
        __syncthreads();   // protect xt before next tile overwrite
    }
}

// ---------------------------------------------------------------------------
// Kernel 2 (fused seq + input-gate GEMM + A->out copy): ONE block per t.
__global__ __launch_bounds__(256) void seqgates_kernel(
    const float* __restrict__ A, const float* __restrict__ W_gcn,
    const float* __restrict__ b_gcn, const float* __restrict__ W_ih,
    const float* __restrict__ b_ih, const float* __restrict__ b_hh,
    float* __restrict__ out, float* __restrict__ ws) {
    int t = blockIdx.x;
    int tid = threadIdx.x;

    // A -> out[16:] copy: one coalesced element per (block, thread)
    {
        int gid = t * 256 + tid;
        if (gid < K_ * V_ * V_) out[16 + gid] = A[gid];
    }

    __shared__ float xaS[N_][K_ * CIN_];
    __shared__ __align__(16) float seqS[N_][COUT_];
    __shared__ float saS[K_];

    if (tid < K_) saS[tid] = ws[WS_SA + tid];
    #pragma unroll
    for (int r = 0; r < 3; ++r) {
        int i = tid + r * 256;
        if (i < N_ * K_ * CIN_) {
            int n = i / (K_ * CIN_), kc = i % (K_ * CIN_);
            xaS[n][kc] = ws[WS_XA + (long)(n * T_ + t) * (K_ * CIN_) + kc];
        }
    }
    __syncthreads();

    // Phase 1: thread (n = tid>>4, c0 = (tid&15)*4) computes 4 seq entries.
    {
        int n = tid >> 4, c0 = (tid & 15) * 4;
        #pragma unroll
        for (int cc = 0; cc < 4; ++cc) {
            int c = c0 + cc;
            float s = 0.f;
            #pragma unroll
            for (int k = 0; k < K_; ++k) {
                s = fmaf(b_gcn[k * COUT_ + c], saS[k], s);
                const float* wrow = W_gcn + (long)(k * COUT_ + c) * CIN_;
                #pragma unroll
                for (int ci = 0; ci < CIN_; ++ci)
                    s = fmaf(wrow[ci], xaS[n][k * CIN_ + ci], s);
            }
            seqS[n][c] = s;
        }
    }
    __syncthreads();

    // Phase 2: thread g: 16 accumulators over n; W_ih row streamed as float4.
    {
        int g = tid;
        float acc[N_];
        #pragma unroll
        for (int n = 0; n < N_; ++n) acc[n] = 0.f;
        const float4* wrow4 = (const float4*)(W_ih + (long)g * H_);
        #pragma unroll
        for (int c4 = 0; c4 < H_ / 4; ++c4) {
            float4 w4 = wrow4[c4];
            #pragma unroll
            for (int n = 0; n < N_; ++n) {
                float4 s4 = ((const float4*)seqS[n])[c4];  // LDS broadcast
                acc[n] = fmaf(w4.x, s4.x, acc[n]);
                acc[n] = fmaf(w4.y, s4.y, acc[n]);
                acc[n] = fmaf(w4.z, s4.z, acc[n]);
                acc[n] = fmaf(w4.w, s4.w, acc[n]);
            }
        }
        float bias = b_ih[g] + b_hh[g];
        #pragma unroll
        for (int n = 0; n < N_; ++n)
            ws[WS_XW + (long)(t * N_ + n) * G_ + g] = acc[n] + bias;
    }
}

// ---------------------------------------------------------------------------
// Kernel 3: sequential LSTM scan — R12 verbatim (measured floor: 260us over
// ten structural variants, R3-R14; insensitive to weight tier / barrier
// count / exchange mechanism; batch-pairing scales time with work).
__global__ __launch_bounds__(256, 1) void lstm_kernel(
    const float* __restrict__ W_hh, const float* __restrict__ W_fc,
    const float* __restrict__ b_fc, const float* __restrict__ ws,
    float* __restrict__ out) {
    int n = blockIdx.x;
    int w = threadIdx.x >> 6;     // gate type (torch order: i,f,g,o)
    int lane = threadIdx.x & 63;  // gate index / h index

    const f32x4* wr = (const f32x4*)(W_hh + (long)(w * H_ + lane) * H_);
    f32x4 w0, w1, w2, w3, w4, w5, w6, w7, w8, w9, w10, w11, w12, w13, w14, w15;
    #define WLOAD(i) \
        asm volatile("global_load_dwordx4 %0, %1, off" : "=v"(w##i) : "v"(wr + i));
    WLOAD(0)  WLOAD(1)  WLOAD(2)  WLOAD(3)
    WLOAD(4)  WLOAD(5)  WLOAD(6)  WLOAD(7)
    WLOAD(8)  WLOAD(9)  WLOAD(10) WLOAD(11)
    WLOAD(12) WLOAD(13) WLOAD(14) WLOAD(15)
    #undef WLOAD
    asm volatile("s_waitcnt vmcnt(0)" ::: "memory");

    __shared__ __align__(16) float hS[H_];
    __shared__ float gbuf[4][H_];

    if (threadIdx.x < H_) hS[threadIdx.x] = 0.f;
    float ccell = 0.f, hlast = 0.f;   // live only in wave 0
    __syncthreads();

    const float* xw = ws + WS_XW + (long)n * G_ + (w * H_ + lane);
    float x0 = xw[0];
    float x1 = xw[(long)N_ * G_];

    for (int t = 0; t < T_; ++t) {
        float gate = x0;
        x0 = x1;
        if (t + 2 < T_) x1 = xw[(long)(t + 2) * N_ * G_];

        float a0 = 0.f, a1 = 0.f, a2 = 0.f, a3 = 0.f;
        const float4* h4 = (const float4*)hS;
        #define DOT4(i)                            \
            {                                      \
                float4 hv = h4[i];                 \
                a0 = fmaf(w##i[0], hv.x, a0);      \
                a1 = fmaf(w##i[1], hv.y, a1);      \
                a2 = fmaf(w##i[2], hv.z, a2);      \
                a3 = fmaf(w##i[3], hv.w, a3);      \
            }
        DOT4(0)  DOT4(1)  DOT4(2)  DOT4(3)
        DOT4(4)  DOT4(5)  DOT4(6)  DOT4(7)
        DOT4(8)  DOT4(9)  DOT4(10) DOT4(11)
        DOT4(12) DOT4(13) DOT4(14) DOT4(15)
        #undef DOT4
        gate += (a0 + a1) + (a2 + a3);

        gbuf[w][lane] = gate;
        __syncthreads();               // B1: gates visible
        if (w == 0) {
            float iv = fast_sig(gate);           // own gate == i
            float fv = fast_sig(gbuf[1][lane]);
            float gv = fast_tanh(gbuf[2][lane]);
            float ov = fast_sig(gbuf[3][lane]);
            ccell = fmaf(fv, ccell, iv * gv);
            hlast = ov * fast_tanh(ccell);
            hS[lane] = hlast;
        }
        __syncthreads();               // B2: new h visible
    }

    if (w == 0) {
        float p = hlast * W_fc[lane];
        #pragma unroll
        for (int m = 1; m < 64; m <<= 1) p += __shfl_xor(p, m);
        if (lane == 0) out[n] = p + b_fc[0];
    }
}

// ---------------------------------------------------------------------------
extern "C" void kernel_launch(void* const* d_in, const int* in_sizes, int n_in,
                              void* d_out, int out_size, void* d_ws, size_t ws_size,
                              hipStream_t stream) {
    const float* x     = (const float*)d_in[0];
    const float* A     = (const float*)d_in[1];
    const float* W_gcn = (const float*)d_in[2];
    const float* b_gcn = (const float*)d_in[3];
    const float* W_ih  = (const float*)d_in[4];
    const float* W_hh  = (const float*)d_in[5];
    const float* b_ih  = (const float*)d_in[6];
    const float* b_hh  = (const float*)d_in[7];
    const float* W_fc  = (const float*)d_in[8];
    const float* b_fc  = (const float*)d_in[9];
    float* out = (float*)d_out;
    float* ws  = (float*)d_ws;

    // 1) xa2: in-block a + tiled xa dots; block 256 computes sa
    xa2_kernel<<<257, 256, 0, stream>>>(x, A, ws);
    // 2) fused seq + input-side gate GEMM + A->out copy (one block per t)
    seqgates_kernel<<<T_, 256, 0, stream>>>(A, W_gcn, b_gcn, W_ih, b_ih, b_hh,
                                            out, ws);
    // 3) sequential LSTM scan + final FC (R12 floor)
    lstm_kernel<<<N_, 256, 0, stream>>>(W_hh, W_fc, b_fc, ws, out);
}

// Round 16
// 349.777 us; speedup vs baseline: 1.6604x; 1.3405x over previous
//
#include <hip/hip_runtime.h>
#include <math.h>

#define N_    16
#define CIN_  16
#define T_    512
#define V_    200
#define K_    3
#define COUT_ 64
#define H_    64
#define G_    256  // 4*H

// Workspace layout (float offsets):
//   a  : [0, 600)                 a[k][v] = sum_w A[k,v,w] / V
//   sa : [640, 643)               sa[k] = sum_{v,w} A[k,v,w] / V
//   xa : [1024, 1024+16*512*48)   xa[n][t][k*16+ci]
//   xW : [WS_XW, +512*16*256)     xW[t][n][g]  (gate pre-activations, input side)
#define WS_A  0
#define WS_SA 640
#define WS_XA 1024
#define WS_XW (WS_XA + N_ * T_ * K_ * CIN_)

typedef __attribute__((ext_vector_type(4))) float f32x4;

// fast activations: v_exp_f32-based, ~1e-6 rel err, saturate correctly
__device__ __forceinline__ float fast_sig(float x) {
    return __builtin_amdgcn_rcpf(1.f + __expf(-x));
}
__device__ __forceinline__ float fast_tanh(float x) {
    return fmaf(-2.f, __builtin_amdgcn_rcpf(1.f + __expf(2.f * x)), 1.f);
}

// ---------------------------------------------------------------------------
// Kernel 1 (fused prep): blocks [0, NCOPY) copy A->out[16:] (blocks 0-2 also
// compute a[k][v]); blocks NCOPY+k (k=0..2) reduce A[k] to sa[k].
#define NCOPY ((K_ * V_ * V_ + 255) / 256)
__global__ __launch_bounds__(256) void prep_kernel(const float* __restrict__ A,
                                                   float* __restrict__ out,
                                                   float* __restrict__ ws) {
    int b = blockIdx.x;
    if (b < NCOPY) {
        int tid = b * 256 + threadIdx.x;
        if (tid < K_ * V_ * V_) out[16 + tid] = A[tid];
        if (tid < K_ * V_) {
            const float* row = A + (long)tid * V_;
            float s = 0.f;
            for (int w = 0; w < V_; ++w) s += row[w];
            ws[WS_A + tid] = s * (1.0f / V_);
        }
    } else {
        int k = b - NCOPY;                      // 0..2
        const float* Ak = A + (long)k * V_ * V_;
        float s = 0.f;
        for (int i = threadIdx.x; i < V_ * V_; i += 256) s += Ak[i];
        #pragma unroll
        for (int m = 1; m < 64; m <<= 1) s += __shfl_xor(s, m);
        __shared__ float red[4];
        if ((threadIdx.x & 63) == 0) red[threadIdx.x >> 6] = s;
        __syncthreads();
        if (threadIdx.x == 0)
            ws[WS_SA + k] = (red[0] + red[1] + red[2] + red[3]) * (1.0f / V_);
    }
}

// ---------------------------------------------------------------------------
// Kernel 2 (tiled xa): xa[n][t][k*16+ci] = sum_v x[n][ci][t][v] * a[k][v]
// One block per (n, ci, 64-t chunk) = 2048 blocks (R15 showed consolidating
// this into 256 serial-loop blocks costs ~115us — keep it wide).
#define TT 64
#define PADV 204
__global__ __launch_bounds__(256) void xa_kernel(const float* __restrict__ x,
                                                 float* __restrict__ ws) {
    __shared__ __align__(16) float xt[TT * PADV];
    __shared__ __align__(16) float aS[K_ * V_];
    int tid = threadIdx.x;
    int b = blockIdx.x;
    int tchunk = b & 7;
    int ci = (b >> 3) & 15;
    int n = b >> 7;
    int t0 = tchunk * TT;

    for (int i = tid; i < K_ * V_; i += 256) aS[i] = ws[WS_A + i];

    const float4* xg4 =
        (const float4*)(x + ((long)(n * CIN_ + ci) * T_ + t0) * V_);
    for (int j = tid; j < TT * (V_ / 4); j += 256) {
        float4 v = xg4[j];
        int t = j / (V_ / 4), v4 = (j % (V_ / 4)) * 4;
        *(float4*)(xt + t * PADV + v4) = v;
    }
    __syncthreads();

    int t_local = tid & 63;
    int k = tid >> 6;            // waves 0..2 active, wave 3 idle
    if (k < K_) {
        const float* xr = xt + t_local * PADV;
        const float* ar = aS + k * V_;
        float a0 = 0.f, a1 = 0.f, a2 = 0.f, a3 = 0.f;
        #pragma unroll 5
        for (int v4 = 0; v4 < V_; v4 += 4) {
            float4 xv = *(const float4*)(xr + v4);
            float4 av = *(const float4*)(ar + v4);   // wave-uniform broadcast
            a0 = fmaf(xv.x, av.x, a0);
            a1 = fmaf(xv.y, av.y, a1);
            a2 = fmaf(xv.z, av.z, a2);
            a3 = fmaf(xv.w, av.w, a3);
        }
        float s = (a0 + a1) + (a2 + a3);
        ws[WS_XA + ((long)n * T_ + (t0 + t_local)) * (K_ * CIN_) + k * CIN_ + ci] = s;
    }
}

// ---------------------------------------------------------------------------
// Kernel 3 (fused seq + input-gate GEMM): ONE block per t (512 blocks).
__global__ __launch_bounds__(256) void seqgates_kernel(
    const float* __restrict__ W_gcn, const float* __restrict__ b_gcn,
    const float* __restrict__ W_ih, const float* __restrict__ b_ih,
    const float* __restrict__ b_hh, float* __restrict__ ws) {
    int t = blockIdx.x;
    int tid = threadIdx.x;
    __shared__ float xaS[N_][K_ * CIN_];
    __shared__ __align__(16) float seqS[N_][COUT_];
    __shared__ float saS[K_];

    if (tid < K_) saS[tid] = ws[WS_SA + tid];
    #pragma unroll
    for (int r = 0; r < 3; ++r) {
        int i = tid + r * 256;
        if (i < N_ * K_ * CIN_) {
            int n = i / (K_ * CIN_), kc = i % (K_ * CIN_);
            xaS[n][kc] = ws[WS_XA + (long)(n * T_ + t) * (K_ * CIN_) + kc];
        }
    }
    __syncthreads();

    // Phase 1: thread (n = tid>>4, c0 = (tid&15)*4) computes 4 seq entries.
    {
        int n = tid >> 4, c0 = (tid & 15) * 4;
        #pragma unroll
        for (int cc = 0; cc < 4; ++cc) {
            int c = c0 + cc;
            float s = 0.f;
            #pragma unroll
            for (int k = 0; k < K_; ++k) {
                s = fmaf(b_gcn[k * COUT_ + c], saS[k], s);
                const float* wrow = W_gcn + (long)(k * COUT_ + c) * CIN_;
                #pragma unroll
                for (int ci = 0; ci < CIN_; ++ci)
                    s = fmaf(wrow[ci], xaS[n][k * CIN_ + ci], s);
            }
            seqS[n][c] = s;
        }
    }
    __syncthreads();

    // Phase 2: thread g: 16 accumulators over n; W_ih row streamed as float4.
    {
        int g = tid;
        float acc[N_];
        #pragma unroll
        for (int n = 0; n < N_; ++n) acc[n] = 0.f;
        const float4* wrow4 = (const float4*)(W_ih + (long)g * H_);
        #pragma unroll
        for (int c4 = 0; c4 < H_ / 4; ++c4) {
            float4 w4 = wrow4[c4];
            #pragma unroll
            for (int n = 0; n < N_; ++n) {
                float4 s4 = ((const float4*)seqS[n])[c4];  // LDS broadcast
                acc[n] = fmaf(w4.x, s4.x, acc[n]);
                acc[n] = fmaf(w4.y, s4.y, acc[n]);
                acc[n] = fmaf(w4.z, s4.z, acc[n]);
                acc[n] = fmaf(w4.w, s4.w, acc[n]);
            }
        }
        float bias = b_ih[g] + b_hh[g];
        #pragma unroll
        for (int n = 0; n < N_; ++n)
            ws[WS_XW + (long)(t * N_ + n) * G_ + g] = acc[n] + bias;
    }
}

// ---------------------------------------------------------------------------
// Kernel 4: sequential LSTM scan — R12 structure + amdgpu_waves_per_eu(1,1).
// Ledger R3-R14: step cost is a tier-invariant 64KB/step weight stream
// (L2 = scratch = LDS = ~1220-1300cy/step); escape requires VGPR residency,
// which the allocator denied 5 times (VGPR_Count pinned 44-56, spilling even
// asm-volatile outputs to scratch) -> its occupancy target caps the budget.
// waves_per_eu(1,1) pins the budget to 1 wave/EU = 512 VGPRs explicitly.
// Falsifier: VGPR_Count >= 130, lstm -> ~110-160us. If VGPR stays <= 64,
// the allocator is beyond source control and this pipeline is the floor.
__global__ __attribute__((amdgpu_waves_per_eu(1, 1)))
__launch_bounds__(256) void lstm_kernel(
    const float* __restrict__ W_hh, const float* __restrict__ W_fc,
    const float* __restrict__ b_fc, const float* __restrict__ ws,
    float* __restrict__ out) {
    int n = blockIdx.x;
    int w = threadIdx.x >> 6;     // gate type (torch order: i,f,g,o)
    int lane = threadIdx.x & 63;  // gate index / h index

    // One-time, non-rematerializable load of this thread's W_hh row.
    const f32x4* wr = (const f32x4*)(W_hh + (long)(w * H_ + lane) * H_);
    f32x4 w0, w1, w2, w3, w4, w5, w6, w7, w8, w9, w10, w11, w12, w13, w14, w15;
    #define WLOAD(i) \
        asm volatile("global_load_dwordx4 %0, %1, off" : "=v"(w##i) : "v"(wr + i));
    WLOAD(0)  WLOAD(1)  WLOAD(2)  WLOAD(3)
    WLOAD(4)  WLOAD(5)  WLOAD(6)  WLOAD(7)
    WLOAD(8)  WLOAD(9)  WLOAD(10) WLOAD(11)
    WLOAD(12) WLOAD(13) WLOAD(14) WLOAD(15)
    #undef WLOAD
    asm volatile("s_waitcnt vmcnt(0)" ::: "memory");

    __shared__ __align__(16) float hS[H_];
    __shared__ float gbuf[4][H_];

    if (threadIdx.x < H_) hS[threadIdx.x] = 0.f;
    float ccell = 0.f, hlast = 0.f;   // live only in wave 0
    __syncthreads();

    const float* xw = ws + WS_XW + (long)n * G_ + (w * H_ + lane);
    float x0 = xw[0];
    float x1 = xw[(long)N_ * G_];

    for (int t = 0; t < T_; ++t) {
        float gate = x0;
        x0 = x1;
        if (t + 2 < T_) x1 = xw[(long)(t + 2) * N_ * G_];

        float a0 = 0.f, a1 = 0.f, a2 = 0.f, a3 = 0.f;
        const float4* h4 = (const float4*)hS;
        #define DOT4(i)                            \
            {                                      \
                float4 hv = h4[i];                 \
                a0 = fmaf(w##i[0], hv.x, a0);      \
                a1 = fmaf(w##i[1], hv.y, a1);      \
                a2 = fmaf(w##i[2], hv.z, a2);      \
                a3 = fmaf(w##i[3], hv.w, a3);      \
            }
        DOT4(0)  DOT4(1)  DOT4(2)  DOT4(3)
        DOT4(4)  DOT4(5)  DOT4(6)  DOT4(7)
        DOT4(8)  DOT4(9)  DOT4(10) DOT4(11)
        DOT4(12) DOT4(13) DOT4(14) DOT4(15)
        #undef DOT4
        gate += (a0 + a1) + (a2 + a3);

        gbuf[w][lane] = gate;
        __syncthreads();               // B1: gates visible
        if (w == 0) {
            float iv = fast_sig(gate);           // own gate == i
            float fv = fast_sig(gbuf[1][lane]);
            float gv = fast_tanh(gbuf[2][lane]);
            float ov = fast_sig(gbuf[3][lane]);
            ccell = fmaf(fv, ccell, iv * gv);
            hlast = ov * fast_tanh(ccell);
            hS[lane] = hlast;
        }
        __syncthreads();               // B2: new h visible
    }

    if (w == 0) {
        float p = hlast * W_fc[lane];
        #pragma unroll
        for (int m = 1; m < 64; m <<= 1) p += __shfl_xor(p, m);
        if (lane == 0) out[n] = p + b_fc[0];
    }
}

// ---------------------------------------------------------------------------
extern "C" void kernel_launch(void* const* d_in, const int* in_sizes, int n_in,
                              void* d_out, int out_size, void* d_ws, size_t ws_size,
                              hipStream_t stream) {
    const float* x     = (const float*)d_in[0];
    const float* A     = (const float*)d_in[1];
    const float* W_gcn = (const float*)d_in[2];
    const float* b_gcn = (const float*)d_in[3];
    const float* W_ih  = (const float*)d_in[4];
    const float* W_hh  = (const float*)d_in[5];
    const float* b_ih  = (const float*)d_in[6];
    const float* b_hh  = (const float*)d_in[7];
    const float* W_fc  = (const float*)d_in[8];
    const float* b_fc  = (const float*)d_in[9];
    float* out = (float*)d_out;
    float* ws  = (float*)d_ws;

    // 1) fused: copy A->out, a[k][v], sa[k]
    prep_kernel<<<NCOPY + K_, 256, 0, stream>>>(A, out, ws);
    // 2) tiled xa (one block per (n, ci, 64-t chunk))
    xa_kernel<<<N_ * CIN_ * (T_ / TT), 256, 0, stream>>>(x, ws);
    // 3) fused seq + input-side gate GEMM (one block per t)
    seqgates_kernel<<<T_, 256, 0, stream>>>(W_gcn, b_gcn, W_ih, b_ih, b_hh, ws);
    // 4) sequential LSTM scan + final FC
    lstm_kernel<<<N_, 256, 0, stream>>>(W_hh, W_fc, b_fc, ws, out);
}